// Round 2
// baseline (1033.075 us; speedup 1.0000x reference)
//
#include <hip/hip_runtime.h>
#include <hip/hip_bf16.h>
#include <cstdint>
#include <cstddef>

#define B_ 4
#define S_ 8192
#define L_ 512
#define DIM 1024
#define NUM_HEADS 16
#define HEAD_DIM 64
#define SCHUNK 4096
#define SCALE 0.125f
#define L2E 1.44269504088896f

typedef __bf16 bf16;
typedef __bf16 bf16x8 __attribute__((ext_vector_type(8)));
typedef float f32x4 __attribute__((ext_vector_type(4)));

#define AS1 __attribute__((address_space(1)))
#define AS3 __attribute__((address_space(3)))
#define GLDS(g, l) __builtin_amdgcn_global_load_lds((const AS1 void*)(g), (AS3 void*)(l), 16, 0, 0)
#define LGKM_FENCE() asm volatile("s_waitcnt lgkmcnt(0)" ::: "memory")
#define MFMA16(a, b, c) __builtin_amdgcn_mfma_f32_16x16x32_bf16((a), (b), (c), 0, 0, 0)

// ---------------------------------------------------------------------------
// Dtype detector: bf16 data has exponent field (bits 14:7 of each 16-bit
// element) concentrated in [117,129] for N(0,1); fp32 words at the same bit
// positions hold uniform mantissa bits (~5% hit rate). 256-word vote.
// flag = 1 -> inputs are fp32; flag = 0 -> inputs are bf16.
// ---------------------------------------------------------------------------
__global__ void detect_dtype(const unsigned int* __restrict__ x, int* __restrict__ flag) {
  int lane = threadIdx.x;  // 64 threads
  int cnt = 0;
  for (int i = 0; i < 4; ++i) {
    unsigned int w = x[lane * 4 + i];
    unsigned int e = (w >> 7) & 0xFFu;  // low-element exponent if bf16
    cnt += (e >= 117u && e <= 129u) ? 1 : 0;
  }
  cnt += __shfl_xor(cnt, 1);
  cnt += __shfl_xor(cnt, 2);
  cnt += __shfl_xor(cnt, 4);
  cnt += __shfl_xor(cnt, 8);
  cnt += __shfl_xor(cnt, 16);
  cnt += __shfl_xor(cnt, 32);
  if (lane == 0) *flag = (cnt < 128) ? 1 : 0;
}

// Normalize a tensor to bf16 in ws (pass-through if already bf16).
__global__ void to_bf16_kernel(const void* __restrict__ src, bf16* __restrict__ dst,
                               int n, const int* __restrict__ flagp) {
  int i = (blockIdx.x * 256 + threadIdx.x) * 4;
  if (i >= n) return;
  if (*flagp != 0) {
    const float* s = (const float*)src;
    for (int j = 0; j < 4 && i + j < n; ++j) dst[i + j] = (bf16)s[i + j];
  } else {
    const bf16* s = (const bf16*)src;
    for (int j = 0; j < 4 && i + j < n; ++j) dst[i + j] = s[i + j];
  }
}

// ---------------------------------------------------------------------------
// NT GEMM: C[m][n] = sum_k A[m][k] * Bw[n][k] (+ bias[n])
// 128x128 tile, 4 waves 2x2, 16x16x32 bf16 MFMA, global_load_lds width 16,
// XOR chunk swizzle (2-way LDS conflicts = free).
// A_FROM_X: A rows are x with chunked row map (m>>12)*8192 + srow0 + (m&4095),
//           dual-dtype staging (fp32 -> convert in VGPRs -> ds_write_b128).
// DUAL_OUT: epilogue writes f32 or bf16 per flag.
// ---------------------------------------------------------------------------
template<int A_FROM_X, int HAS_BIAS, int DUAL_OUT>
__global__ __launch_bounds__(256) void gemm_nt(
    const void* __restrict__ Ap, const bf16* __restrict__ Bw,
    void* __restrict__ Cp, const bf16* __restrict__ bias,
    int M, int N, int K, int srow0, const int* __restrict__ flagp)
{
  __shared__ __align__(16) bf16 lA[128 * 32];
  __shared__ __align__(16) bf16 lB[128 * 32];
  const int tid = threadIdx.x;
  const int lane = tid & 63, quad = lane >> 4, l16 = lane & 15, wave = tid >> 6;
  const int wm = wave >> 1, wn = wave & 1;
  const int bm = blockIdx.y, bn = blockIdx.x;
  const bool af32 = A_FROM_X ? (*flagp != 0) : false;

  f32x4 acc[4][4] = {};
  const int nK = K >> 5;
  for (int kb = 0; kb < nK; ++kb) {
    __syncthreads();
    for (int i = 0; i < 2; ++i) {
      int e = i * 256 + tid;
      int row = e >> 2, cp = e & 3, gcp = cp ^ ((row >> 1) & 3);
      int m = bm * 128 + row;
      size_t arow = A_FROM_X ? (size_t)((m >> 12) * 8192 + srow0 + (m & 4095)) : (size_t)m;
      if (A_FROM_X && af32) {
        const float* ga = (const float*)Ap + arow * K + kb * 32 + gcp * 8;
        f32x4 lo = *(const f32x4*)ga;
        f32x4 hi = *(const f32x4*)(ga + 4);
        bf16x8 w;
        w[0] = (bf16)lo[0]; w[1] = (bf16)lo[1]; w[2] = (bf16)lo[2]; w[3] = (bf16)lo[3];
        w[4] = (bf16)hi[0]; w[5] = (bf16)hi[1]; w[6] = (bf16)hi[2]; w[7] = (bf16)hi[3];
        *(bf16x8*)(lA + e * 8) = w;
      } else {
        const bf16* ga = (const bf16*)Ap + arow * K + kb * 32 + gcp * 8;
        GLDS(ga, lA + e * 8);
      }
      const bf16* gb = Bw + (size_t)(bn * 128 + row) * K + kb * 32 + gcp * 8;
      GLDS(gb, lB + e * 8);
    }
    __syncthreads();

    bf16x8 af[4], bfr[4];
#pragma unroll
    for (int t = 0; t < 4; ++t) {
      int rowA = wm * 64 + t * 16 + l16;
      int ca = quad ^ ((rowA >> 1) & 3);
      af[t] = *(const bf16x8*)(lA + rowA * 32 + ca * 8);
      int rowB = wn * 64 + t * 16 + l16;
      int cb = quad ^ ((rowB >> 1) & 3);
      bfr[t] = *(const bf16x8*)(lB + rowB * 32 + cb * 8);
    }
#pragma unroll
    for (int tm = 0; tm < 4; ++tm)
#pragma unroll
      for (int tn = 0; tn < 4; ++tn)
        acc[tm][tn] = MFMA16(af[tm], bfr[tn], acc[tm][tn]);
  }

  const bool of32 = DUAL_OUT ? (*flagp != 0) : false;
#pragma unroll
  for (int tn = 0; tn < 4; ++tn) {
    int col = bn * 128 + wn * 64 + tn * 16 + l16;
    float bv = HAS_BIAS ? (float)bias[col] : 0.0f;
#pragma unroll
    for (int tm = 0; tm < 4; ++tm) {
#pragma unroll
      for (int r = 0; r < 4; ++r) {
        int rowc = bm * 128 + wm * 64 + tm * 16 + quad * 4 + r;
        float v = acc[tm][tn][r] + bv;
        if (DUAL_OUT && of32) ((float*)Cp)[(size_t)rowc * N + col] = v;
        else                  ((bf16*)Cp)[(size_t)rowc * N + col] = (bf16)v;
      }
    }
  }
}

// ---------------------------------------------------------------------------
// Attention pass over one S-chunk (4096 keys). Grid (L/64, H, B), 4 waves.
// Fuses: q-projection mini-GEMM (64lx64d per block from latents/w_q, routed
// C-layout -> pbuf -> A-layout), K staged via global_load_lds (XOR swizzle),
// V staged transposed into LDS (group-XOR swizzle; write & b128 read banks
// 2-way = free). Online softmax state (m,l,O-f32) persists in ws between
// the two chunk passes.
// ---------------------------------------------------------------------------
template<int FIRST, int LAST>
__global__ __launch_bounds__(256) void attn_pass(
    const bf16* __restrict__ latb, const bf16* __restrict__ wqb,
    const bf16* __restrict__ kc, const bf16* __restrict__ vc,
    float* __restrict__ Ost, float* __restrict__ mst, float* __restrict__ lst,
    bf16* __restrict__ ao)
{
  __shared__ __align__(16) bf16 lK[64 * 64];
  __shared__ __align__(16) bf16 lV[64][72];
  __shared__ __align__(16) bf16 pbuf[4][16][72];
  const int tid = threadIdx.x;
  const int lane = tid & 63, quad = lane >> 4, l16 = lane & 15, wave = tid >> 6;
  const int b = blockIdx.z, h = blockIdx.y, lt = blockIdx.x;

  // ---- mini q-GEMM: Q-tile 64l x 64d, K=1024 in 16 chunks of 64 ----
  bf16* lW = &lV[0][0];  // reuse 8KB of lV
  f32x4 qacc[4] = {};
  const int lrow0 = b * L_ + lt * 64;
  for (int kb = 0; kb < 16; ++kb) {
    __syncthreads();
    for (int i = 0; i < 2; ++i) {
      int e = i * 256 + tid;
      int row = e >> 3, cp = e & 7, gcp = cp ^ (row & 7);
      const bf16* gl = latb + (size_t)(lrow0 + row) * DIM + kb * 64 + gcp * 8;
      const bf16* gw = wqb + (size_t)(h * 64 + row) * DIM + kb * 64 + gcp * 8;
      GLDS(gl, lK + e * 8);
      GLDS(gw, lW + e * 8);
    }
    __syncthreads();
#pragma unroll
    for (int half = 0; half < 2; ++half) {
      int ra = wave * 16 + l16;
      int pca = (half * 4 + quad) ^ (ra & 7);
      bf16x8 afq = *(const bf16x8*)(lK + ra * 64 + pca * 8);
#pragma unroll
      for (int nt = 0; nt < 4; ++nt) {
        int rb = nt * 16 + l16;
        int pcb = (half * 4 + quad) ^ (rb & 7);
        bf16x8 bfq = *(const bf16x8*)(lW + rb * 64 + pcb * 8);
        qacc[nt] = MFMA16(afq, bfq, qacc[nt]);
      }
    }
  }
  // C-layout -> pbuf -> A-layout q fragments (per-wave buffer, no barrier)
#pragma unroll
  for (int nt = 0; nt < 4; ++nt)
#pragma unroll
    for (int r = 0; r < 4; ++r)
      pbuf[wave][quad * 4 + r][nt * 16 + l16] = (bf16)qacc[nt][r];
  LGKM_FENCE();
  bf16x8 qf0 = *(const bf16x8*)&pbuf[wave][l16][quad * 8];
  bf16x8 qf1 = *(const bf16x8*)&pbuf[wave][l16][32 + quad * 8];

  // ---- state ----
  f32x4 acc[4] = {};
  float m_i[4], l_i[4];
  if (FIRST) {
#pragma unroll
    for (int r = 0; r < 4; ++r) { m_i[r] = -1e30f; l_i[r] = 0.0f; }
  } else {
#pragma unroll
    for (int r = 0; r < 4; ++r) {
      int l = lt * 64 + wave * 16 + quad * 4 + r;
      int si = (b * NUM_HEADS + h) * L_ + l;
      m_i[r] = mst[si]; l_i[r] = lst[si];
    }
#pragma unroll
    for (int t4 = 0; t4 < 4; ++t4)
#pragma unroll
      for (int r = 0; r < 4; ++r) {
        int l = lt * 64 + wave * 16 + quad * 4 + r;
        acc[t4][r] = Ost[(size_t)(b * L_ + l) * DIM + h * 64 + t4 * 16 + l16];
      }
  }

  // ---- S-loop: 64 tiles of 64 keys ----
  for (int s0 = 0; s0 < SCHUNK; s0 += 64) {
    __syncthreads();
    // stage K (swizzled: LDS slot (row,cp) holds global chunk cp^(row&7))
    for (int i = 0; i < 2; ++i) {
      int e = i * 256 + tid;
      int row = e >> 3, cp = e & 7, gcp = cp ^ (row & 7);
      const bf16* gk = kc + (size_t)(b * SCHUNK + s0 + row) * DIM + h * 64 + gcp * 8;
      GLDS(gk, lK + e * 8);
    }
    // stage V transposed: lV[c][ ((s>>3)^(c>>3))*8 + (s&7) ]
    for (int i = 0; i < 2; ++i) {
      int e = i * 256 + tid;
      int row = e >> 3, cc = e & 7;
      bf16x8 vv = *(const bf16x8*)(vc + (size_t)(b * SCHUNK + s0 + row) * DIM + h * 64 + cc * 8);
      int pg = (row >> 3) ^ cc;
#pragma unroll
      for (int j = 0; j < 8; ++j)
        lV[cc * 8 + j][pg * 8 + (row & 7)] = vv[j];
    }
    __syncthreads();

    // scores: 4 key-subtiles of 16
    f32x4 sc[4];
#pragma unroll
    for (int kt = 0; kt < 4; ++kt) {
      int rk = kt * 16 + l16;
      int p0c = quad ^ (rk & 7);
      int p1c = (4 + quad) ^ (rk & 7);
      bf16x8 kf0 = *(const bf16x8*)(lK + rk * 64 + p0c * 8);
      bf16x8 kf1 = *(const bf16x8*)(lK + rk * 64 + p1c * 8);
      f32x4 s4 = {};
      s4 = MFMA16(qf0, kf0, s4);
      s4 = MFMA16(qf1, kf1, s4);
      sc[kt] = s4;
    }

    // online softmax (rows = quad*4+r, cols across 16 lanes)
    float alpha[4];
#pragma unroll
    for (int r = 0; r < 4; ++r) {
      float x0 = sc[0][r] * SCALE, x1 = sc[1][r] * SCALE;
      float x2 = sc[2][r] * SCALE, x3 = sc[3][r] * SCALE;
      float t = fmaxf(fmaxf(x0, x1), fmaxf(x2, x3));
      t = fmaxf(t, __shfl_xor(t, 1, 16));
      t = fmaxf(t, __shfl_xor(t, 2, 16));
      t = fmaxf(t, __shfl_xor(t, 4, 16));
      t = fmaxf(t, __shfl_xor(t, 8, 16));
      float mn = fmaxf(m_i[r], t);
      float a0 = exp2f((x0 - mn) * L2E);
      float a1 = exp2f((x1 - mn) * L2E);
      float a2 = exp2f((x2 - mn) * L2E);
      float a3 = exp2f((x3 - mn) * L2E);
      alpha[r] = exp2f((m_i[r] - mn) * L2E);
      float rs = a0 + a1 + a2 + a3;
      rs += __shfl_xor(rs, 1, 16);
      rs += __shfl_xor(rs, 2, 16);
      rs += __shfl_xor(rs, 4, 16);
      rs += __shfl_xor(rs, 8, 16);
      l_i[r] = l_i[r] * alpha[r] + rs;
      m_i[r] = mn;
      pbuf[wave][quad * 4 + r][l16]      = (bf16)a0;
      pbuf[wave][quad * 4 + r][16 + l16] = (bf16)a1;
      pbuf[wave][quad * 4 + r][32 + l16] = (bf16)a2;
      pbuf[wave][quad * 4 + r][48 + l16] = (bf16)a3;
    }
#pragma unroll
    for (int t4 = 0; t4 < 4; ++t4)
#pragma unroll
      for (int r = 0; r < 4; ++r)
        acc[t4][r] *= alpha[r];

    LGKM_FENCE();
    // PV: two 32-key halves
#pragma unroll
    for (int half = 0; half < 2; ++half) {
      bf16x8 pf = *(const bf16x8*)&pbuf[wave][l16][half * 32 + quad * 8];
#pragma unroll
      for (int t4 = 0; t4 < 4; ++t4) {
        int c = t4 * 16 + l16;
        int pg = (half * 4 + quad) ^ (c >> 3);
        bf16x8 vf = *(const bf16x8*)&lV[c][pg * 8];
        acc[t4] = MFMA16(pf, vf, acc[t4]);
      }
    }
  }

  // ---- epilogue ----
  if (LAST) {
#pragma unroll
    for (int t4 = 0; t4 < 4; ++t4)
#pragma unroll
      for (int r = 0; r < 4; ++r) {
        int l = lt * 64 + wave * 16 + quad * 4 + r;
        ao[(size_t)(b * L_ + l) * DIM + h * 64 + t4 * 16 + l16] = (bf16)(acc[t4][r] / l_i[r]);
      }
  } else {
#pragma unroll
    for (int r = 0; r < 4; ++r) {
      int l = lt * 64 + wave * 16 + quad * 4 + r;
      int si = (b * NUM_HEADS + h) * L_ + l;
      if (l16 == 0) { mst[si] = m_i[r]; lst[si] = l_i[r]; }
    }
#pragma unroll
    for (int t4 = 0; t4 < 4; ++t4)
#pragma unroll
      for (int r = 0; r < 4; ++r) {
        int l = lt * 64 + wave * 16 + quad * 4 + r;
        Ost[(size_t)(b * L_ + l) * DIM + h * 64 + t4 * 16 + l16] = acc[t4][r];
      }
  }
}

// ---------------------------------------------------------------------------
extern "C" void kernel_launch(void* const* d_in, const int* in_sizes, int n_in,
                              void* d_out, int out_size, void* d_ws, size_t ws_size,
                              hipStream_t stream)
{
  (void)in_sizes; (void)n_in; (void)out_size; (void)ws_size;
  const void* x       = d_in[0];
  const void* latents = d_in[1];
  const void* w_q     = d_in[2];
  const void* w_kv    = d_in[3];
  const void* w_out   = d_in[4];
  const void* b_out   = d_in[5];

  char* ws = (char*)d_ws;
  int*   flag = (int*)ws;
  bf16*  latb = (bf16*)(ws + ((size_t)1  << 20));   // 4 MB
  bf16*  wqb  = (bf16*)(ws + ((size_t)5  << 20));   // 2 MB
  bf16*  wkvb = (bf16*)(ws + ((size_t)8  << 20));   // 4 MB
  bf16*  wob  = (bf16*)(ws + ((size_t)12 << 20));   // 2 MB
  bf16*  bob  = (bf16*)(ws + ((size_t)14 << 20));   // 2 KB
  float* mst  = (float*)(ws + ((size_t)15 << 20));  // 128 KB
  float* lst  = (float*)(ws + ((size_t)15 << 20) + ((size_t)256 << 10));
  float* Ost  = (float*)(ws + ((size_t)16 << 20));  // 8 MB
  bf16*  ao   = (bf16*)(ws + ((size_t)24 << 20));   // 4 MB
  bf16*  kc   = (bf16*)(ws + ((size_t)28 << 20));   // 32 MB
  bf16*  vc   = (bf16*)(ws + ((size_t)60 << 20));   // 32 MB -> 92 MB total

  detect_dtype<<<1, 64, 0, stream>>>((const unsigned int*)x, flag);

  auto cvt = [&](const void* src, bf16* dst, int n) {
    int blocks = (n / 4 + 255) / 256;
    to_bf16_kernel<<<blocks, 256, 0, stream>>>(src, dst, n, flag);
  };
  cvt(latents, latb, B_ * L_ * DIM);
  cvt(w_q,     wqb,  DIM * DIM);
  cvt(w_kv,    wkvb, 2 * DIM * DIM);
  cvt(w_out,   wob,  DIM * DIM);
  cvt(b_out,   bob,  DIM);

  const int Mx = B_ * SCHUNK;  // 16384
  dim3 gkv(DIM / 128, Mx / 128);
  dim3 gat(L_ / 64, NUM_HEADS, B_);

  // chunk 0
  gemm_nt<1, 0, 0><<<gkv, 256, 0, stream>>>(x, wkvb,            kc, nullptr, Mx, DIM, DIM, 0, flag);
  gemm_nt<1, 0, 0><<<gkv, 256, 0, stream>>>(x, wkvb + DIM*DIM,  vc, nullptr, Mx, DIM, DIM, 0, flag);
  attn_pass<1, 0><<<gat, 256, 0, stream>>>(latb, wqb, kc, vc, Ost, mst, lst, ao);
  // chunk 1
  gemm_nt<1, 0, 0><<<gkv, 256, 0, stream>>>(x, wkvb,            kc, nullptr, Mx, DIM, DIM, SCHUNK, flag);
  gemm_nt<1, 0, 0><<<gkv, 256, 0, stream>>>(x, wkvb + DIM*DIM,  vc, nullptr, Mx, DIM, DIM, SCHUNK, flag);
  attn_pass<0, 1><<<gat, 256, 0, stream>>>(latb, wqb, kc, vc, Ost, mst, lst, ao);

  // out = ao @ w_out^T + b_out
  gemm_nt<0, 1, 1><<<dim3(DIM / 128, (B_ * L_) / 128), 256, 0, stream>>>(
      ao, wob, d_out, bob, B_ * L_, DIM, DIM, 0, flag);
}